// Round 6
// baseline (191.373 us; speedup 1.0000x reference)
//
#include <hip/hip_runtime.h>
#include <cmath>

#define HW   35200          // 200*176
#define CD   128            // C*D

typedef short bf16x8 __attribute__((ext_vector_type(8)));
typedef float f32x4  __attribute__((ext_vector_type(4)));

// ---- workspace float offsets ----
#define OFF_W1B   0         // w1b frag bf16 [2 kh][4 nt][64 lane][8 e] = 4096 bf16
#define OFF_W2B   2048      // w2b frag bf16 [2 kh][2 nt][64][8]        = 2048 bf16
#define OFF_TD    3072      // tD[d][o] fp32 (b1,be1,BN folded)           128 f
#define OFF_TH    3200      // tH[o][h] fp32                            12800 f
#define OFF_TW    16000     // tW[o][w] fp32                            11264 f
#define OFF_B2F   27264     // 32 f
#define OFF_W3F   27296     // 32 f
#define OFF_F0B   27328     // f0b bf16 [4][32][HW][4] = 18022400 bf16 = 9011200 f
#define OFF_F1B   9038528   // f1b bf16 same size

__device__ __forceinline__ float lrelu(float v) { return v >= 0.f ? v : 0.01f * v; }
__device__ __forceinline__ unsigned short f2bf(float f) {   // RNE fp32->bf16
  unsigned u = __float_as_uint(f);
  u = (u + 0x7fffu + ((u >> 16) & 1u)) >> 16;
  return (unsigned short)u;
}
__device__ __forceinline__ float bflo(unsigned u) { return __uint_as_float(u << 16); }
__device__ __forceinline__ float bfhi(unsigned u) { return __uint_as_float(u & 0xffff0000u); }

// ---------------- setup: BN-folded bf16 weight frags + separable PE tables ----------------
__global__ void setup_kernel(const float* __restrict__ w1, const float* __restrict__ b1,
                             const float* __restrict__ g1, const float* __restrict__ be1,
                             const float* __restrict__ w2, const float* __restrict__ b2,
                             const float* __restrict__ g2, const float* __restrict__ be2,
                             const float* __restrict__ w3, const float* __restrict__ b3,
                             float* __restrict__ ws) {
  const float RS = rsqrtf(1.0f + 1e-5f);
  unsigned short* w1b = (unsigned short*)(ws + OFF_W1B);
  unsigned short* w2b = (unsigned short*)(ws + OFF_W2B);
  int i = blockIdx.x * blockDim.x + threadIdx.x;
  if (i < 4096) {                  // w1b: B[k][n], k=kh*32+(l>>4)*8+e (x-ch), n=nt*16+(l&15)
    int e = i & 7, l = (i >> 3) & 63, nt = (i >> 9) & 3, kh = i >> 11;
    int n = nt * 16 + (l & 15);
    int k = kh * 32 + (l >> 4) * 8 + e;
    w1b[i] = f2bf(w1[n * 112 + k] * (g1[n] * RS));
    return;
  }
  i -= 4096;
  if (i < 2048) {                  // w2b
    int e = i & 7, l = (i >> 3) & 63, nt = (i >> 9) & 1, kh = i >> 10;
    int n = nt * 16 + (l & 15);
    int k = kh * 32 + (l >> 4) * 8 + e;
    w2b[i] = f2bf(w2[n * 64 + k] * (g2[n] * RS));
    return;
  }
  i -= 2048;
  if (i < 128) {                   // tD[d][o] = s1*(b1 + w1[64..79]·encD(d)) + be1
    int d = i >> 6, o = i & 63;
    float a = 0.f;
    for (int j = 0; j < 8; ++j) {
      float dv = expf((float)(2 * j) * (-0.5756462732485115f));
      float t  = (float)d * dv;
      a += w1[o * 112 + 64 + j] * sinf(t) + w1[o * 112 + 72 + j] * cosf(t);
    }
    ws[OFF_TD + d * 64 + o] = (g1[o] * RS) * (b1[o] + a) + be1[o];
    return;
  }
  i -= 128;
  if (i < 12800) {                 // tH[o][h]
    int o = i / 200, h = i - o * 200;
    float a = 0.f;
    for (int j = 0; j < 8; ++j) {
      float dv = expf((float)(2 * j) * (-0.5756462732485115f));
      float t  = (float)h * dv;
      a += w1[o * 112 + 80 + j] * sinf(t) + w1[o * 112 + 88 + j] * cosf(t);
    }
    ws[OFF_TH + i] = (g1[o] * RS) * a;
    return;
  }
  i -= 12800;
  if (i < 11264) {                 // tW[o][w]
    int o = i / 176, w = i - o * 176;
    float a = 0.f;
    for (int j = 0; j < 8; ++j) {
      float dv = expf((float)(2 * j) * (-0.5756462732485115f));
      float t  = (float)w * dv;
      a += w1[o * 112 + 96 + j] * sinf(t) + w1[o * 112 + 104 + j] * cosf(t);
    }
    ws[OFF_TW + i] = (g1[o] * RS) * a;
    return;
  }
  i -= 11264;
  if (i < 32) { ws[OFF_B2F + i] = b2[i] * (g2[i] * RS) + be2[i]; return; }
  i -= 32;
  if (i < 32) { ws[OFF_W3F + i] = w3[i]; }
}

// ---------------- pass 1: MFMA MLP; writes fXb = x*wt (bf16) for input inp ----------------
// Block: 64 px, M=128 rows (row = d*64+px), K=64 x-channels; PE folded into acc init.
__global__ __launch_bounds__(256)
void mlp_kernel(const float* __restrict__ x0, const float* __restrict__ x1,
                const float* __restrict__ wtab,
                unsigned short* __restrict__ f0b, unsigned short* __restrict__ f1b) {
  __shared__ alignas(16) unsigned short As[8 * 128 * 8];   // [kgrp][row][8] bf16, 16 KB
  __shared__ alignas(16) unsigned short Hs[8 * 128 * 8];   // h1, 16 KB (lg/wts overlay after death)
  float* lgp  = (float*)Hs;        // [128]  — overlays dead Hs
  float* wtsp = lgp + 128;         // [2][64]

  const int t    = threadIdx.x;
  const int lane = t & 63;
  const int wv   = __builtin_amdgcn_readfirstlane(t >> 6);
  const int px   = lane;
  const int n    = blockIdx.y;
  const int inp  = blockIdx.z;
  const int hw0  = blockIdx.x * 64;
  const float* xn = (inp ? x1 : x0) + (size_t)n * CD * HW;
  unsigned short* dst = inp ? f1b : f0b;
  const unsigned short* w1bu = (const unsigned short*)(wtab + OFF_W1B);
  const unsigned short* w2bu = (const unsigned short*)(wtab + OFF_W2B);

  // ---- stage x (fp32->bf16) into As ----
#pragma unroll
  for (int i2 = 0; i2 < 4; ++i2) {
    const int md = wv * 4 + i2, d = md & 1, m = md >> 1;   // kgrp m, depth d
    float v[8];
#pragma unroll
    for (int e = 0; e < 8; ++e)
      v[e] = xn[(size_t)((m * 8 + e) * 2 + d) * HW + hw0 + px];
    uint4 uu;
    uu.x = (unsigned)f2bf(v[0]) | ((unsigned)f2bf(v[1]) << 16);
    uu.y = (unsigned)f2bf(v[2]) | ((unsigned)f2bf(v[3]) << 16);
    uu.z = (unsigned)f2bf(v[4]) | ((unsigned)f2bf(v[5]) << 16);
    uu.w = (unsigned)f2bf(v[6]) | ((unsigned)f2bf(v[7]) << 16);
    *(uint4*)&As[(unsigned)(m * 128 + d * 64 + px) * 8] = uu;
  }
  __syncthreads();                                   // [1]

  // ---- layer 1: M=128 x K=64 x N=64; wave owns row-tiles {2wv, 2wv+1} ----
  const int rtb = wv * 2, dw = wv >> 1;
  f32x4 acc[2][4];
#pragma unroll
  for (int rti = 0; rti < 2; ++rti)
#pragma unroll
    for (int r = 0; r < 4; ++r) {
      const int row = (rtb + rti) * 16 + (lane >> 4) * 4 + r;
      const int pxr = hw0 + (row & 63);
      const int hh  = pxr / 176;
      const int ww  = pxr - hh * 176;
#pragma unroll
      for (int nt = 0; nt < 4; ++nt) {
        const int o = nt * 16 + (lane & 15);
        acc[rti][nt][r] = wtab[OFF_TD + dw * 64 + o] + wtab[OFF_TH + o * 200 + hh]
                        + wtab[OFF_TW + o * 176 + ww];
      }
    }
#pragma unroll
  for (int kh = 0; kh < 2; ++kh) {
    const bf16x8 a0 = *(const bf16x8*)&As[(unsigned)((kh * 4 + (lane >> 4)) * 128 + (rtb + 0) * 16 + (lane & 15)) * 8];
    const bf16x8 a1 = *(const bf16x8*)&As[(unsigned)((kh * 4 + (lane >> 4)) * 128 + (rtb + 1) * 16 + (lane & 15)) * 8];
#pragma unroll
    for (int nt = 0; nt < 4; ++nt) {
      const bf16x8 b = *(const bf16x8*)&w1bu[(unsigned)((kh * 4 + nt) * 64 + lane) * 8];
      acc[0][nt] = __builtin_amdgcn_mfma_f32_16x16x32_bf16(a0, b, acc[0][nt], 0, 0, 0);
      acc[1][nt] = __builtin_amdgcn_mfma_f32_16x16x32_bf16(a1, b, acc[1][nt], 0, 0, 0);
    }
  }
  // lrelu + h1 -> Hs (bf16); D layout: row=(l>>4)*4+r, col=l&15
#pragma unroll
  for (int rti = 0; rti < 2; ++rti)
#pragma unroll
    for (int nt = 0; nt < 4; ++nt)
#pragma unroll
      for (int r = 0; r < 4; ++r) {
        const int o   = nt * 16 + (lane & 15);
        const int row = (rtb + rti) * 16 + (lane >> 4) * 4 + r;
        Hs[(unsigned)((o >> 3) * 128 + row) * 8 + (o & 7)] = f2bf(lrelu(acc[rti][nt][r]));
      }
  __syncthreads();                                   // [2]

  // ---- layer 2: K=64 x N=32 ----
  f32x4 acc2[2][2];
#pragma unroll
  for (int nt = 0; nt < 2; ++nt) {
    const float bv = wtab[OFF_B2F + nt * 16 + (lane & 15)];
    acc2[0][nt] = (f32x4){bv, bv, bv, bv};
    acc2[1][nt] = acc2[0][nt];
  }
#pragma unroll
  for (int kh = 0; kh < 2; ++kh) {
    const bf16x8 a0 = *(const bf16x8*)&Hs[(unsigned)((kh * 4 + (lane >> 4)) * 128 + (rtb + 0) * 16 + (lane & 15)) * 8];
    const bf16x8 a1 = *(const bf16x8*)&Hs[(unsigned)((kh * 4 + (lane >> 4)) * 128 + (rtb + 1) * 16 + (lane & 15)) * 8];
#pragma unroll
    for (int nt = 0; nt < 2; ++nt) {
      const bf16x8 b = *(const bf16x8*)&w2bu[(unsigned)((kh * 2 + nt) * 64 + lane) * 8];
      acc2[0][nt] = __builtin_amdgcn_mfma_f32_16x16x32_bf16(a0, b, acc2[0][nt], 0, 0, 0);
      acc2[1][nt] = __builtin_amdgcn_mfma_f32_16x16x32_bf16(a1, b, acc2[1][nt], 0, 0, 0);
    }
  }

  // ---- layer 3 + logit reduce (registers only; b3 cancels) ----
  const float w3a = wtab[OFF_W3F + (lane & 15)];
  const float w3b = wtab[OFF_W3F + 16 + (lane & 15)];
  float pr[2][4];
#pragma unroll
  for (int rti = 0; rti < 2; ++rti)
#pragma unroll
    for (int r = 0; r < 4; ++r) {
      float p = w3a * lrelu(acc2[rti][0][r]) + w3b * lrelu(acc2[rti][1][r]);
      p += __shfl_xor(p, 1);
      p += __shfl_xor(p, 2);
      p += __shfl_xor(p, 4);
      p += __shfl_xor(p, 8);
      pr[rti][r] = p;
    }
  __syncthreads();                                   // [3] Hs dead -> overlay safe
#pragma unroll
  for (int rti = 0; rti < 2; ++rti)
#pragma unroll
    for (int r = 0; r < 4; ++r)
      if ((lane & 15) == 0) lgp[(rtb + rti) * 16 + (lane >> 4) * 4 + r] = pr[rti][r];
  __syncthreads();                                   // [4]

  // ---- softmax over 2 depths ----
  if (t < 128) {
    const int pp = t & 63, dd = t >> 6;
    const float lm = lgp[dd * 64 + pp], lo = lgp[(1 - dd) * 64 + pp];
    wtsp[dd * 64 + pp] = 1.f / (1.f + expf(lo - lm));
  }
  __syncthreads();                                   // [5]

  // ---- store fXb = x*wt, bf16 packed [n][k][hw][4] ----
  const float w0 = wtsp[px], w1v = wtsp[64 + px];
#pragma unroll
  for (int i2 = 0; i2 < 8; ++i2) {
    const int k = wv * 8 + i2;   // planes 4k..4k+3 = (c=2k,d0),(2k,d1),(2k+1,d0),(2k+1,d1)
    const unsigned ua = *(const unsigned*)&As[(unsigned)((k >> 2) * 128 + px) * 8 + ((2 * k) & 7)];
    const unsigned ub = *(const unsigned*)&As[(unsigned)((k >> 2) * 128 + 64 + px) * 8 + ((2 * k) & 7)];
    const unsigned short v0 = f2bf(bflo(ua) * w0);
    const unsigned short v1 = f2bf(bflo(ub) * w1v);
    const unsigned short v2 = f2bf(bfhi(ua) * w0);
    const unsigned short v3 = f2bf(bfhi(ub) * w1v);
    uint2 pk;
    pk.x = (unsigned)v0 | ((unsigned)v1 << 16);
    pk.y = (unsigned)v2 | ((unsigned)v3 << 16);
    *(uint2*)&dst[(((size_t)n * 32 + k) * HW + hw0 + px) * 4] = pk;
  }
}

// ---------------- pass 2: pure memory — out = max(f0, bilinear(rot(f1))) ----------------
__global__ __launch_bounds__(256)
void gather_max_kernel(const unsigned short* __restrict__ f0b,
                       const unsigned short* __restrict__ f1b,
                       const float* __restrict__ tp,
                       float* __restrict__ out) {
  // bijective XCD swizzle over 550 tiles (q=68, r=6)
  const int orig = blockIdx.x;
  const int xcd = orig & 7, idx = orig >> 3;
  const int tile = (xcd < 6 ? xcd * 69 : 6 * 69 + (xcd - 6) * 68) + idx;

  const int tix = threadIdx.x;
  const int px  = tix & 63;
  const int q   = tix >> 6;
  const int n   = blockIdx.y;
  const int hw  = tile * 64 + px;
  const int h   = hw / 176;
  const int w   = hw - h * 176;

  const float thp = tp[n * 2 + 0], thc = tp[n * 2 + 1];
  const float gx = 0.2f + 0.4f * (float)w;
  const float gy = -39.8f + 0.4f * (float)h;
  const float c1 = cosf(thc),  s1v = sinf(thc);
  const float p1x = gx * c1 - gy * s1v;
  const float p1y = gx * s1v + gy * c1;
  const float c2 = cosf(-thp), s2v = sinf(-thp);
  const float p2x = p1x * c2 - p1y * s2v;
  const float p2y = p1x * s2v + p1y * c2;
  const float xi = p2x / 0.05f / 8.f;
  const float yi = (p2y - (-40.f)) / 0.05f / 8.f;

  const float xf = floorf(xi), yf = floorf(yi);
  const int x0i = (int)xf, y0i = (int)yf;
  const int x0c = min(max(x0i,     0), 175);
  const int x1c = min(max(x0i + 1, 0), 175);
  const int y0c = min(max(y0i,     0), 199);
  const int y1c = min(max(y0i + 1, 0), 199);
  const float x0f = (float)x0c, x1f = (float)x1c;
  const float y0f = (float)y0c, y1f = (float)y1c;
  const float wa = (x1f - xi) * (y1f - yi);
  const float wb = (x1f - xi) * (yi - y0f);
  const float wc = (xi - x0f) * (y1f - yi);
  const float wd = (xi - x0f) * (yi - y0f);
  const int ta = y0c * 176 + x0c, tb = y1c * 176 + x0c;
  const int tc = y0c * 176 + x1c, td = y1c * 176 + x1c;

#pragma unroll
  for (int i = 0; i < 8; ++i) {
    const int k = q * 8 + i;
    const int cd0 = k * 4;
    const unsigned short* fp1 = f1b + ((size_t)n * 32 + k) * HW * 4;
    const uint2 Ia = *(const uint2*)(fp1 + (size_t)ta * 4);
    const uint2 Ib = *(const uint2*)(fp1 + (size_t)tb * 4);
    const uint2 Ic = *(const uint2*)(fp1 + (size_t)tc * 4);
    const uint2 Id = *(const uint2*)(fp1 + (size_t)td * 4);
    float4 sv;
    sv.x = bflo(Ia.x) * wa + bflo(Ib.x) * wb + bflo(Ic.x) * wc + bflo(Id.x) * wd;
    sv.y = bfhi(Ia.x) * wa + bfhi(Ib.x) * wb + bfhi(Ic.x) * wc + bfhi(Id.x) * wd;
    sv.z = bflo(Ia.y) * wa + bflo(Ib.y) * wb + bflo(Ic.y) * wc + bflo(Id.y) * wd;
    sv.w = bfhi(Ia.y) * wa + bfhi(Ib.y) * wb + bfhi(Ic.y) * wc + bfhi(Id.y) * wd;

    const uint2 F0 = *(const uint2*)(f0b + (((size_t)n * 32 + k) * HW + hw) * 4);

    float* op = out + ((size_t)n * CD + cd0) * HW + hw;
    op[0]              = fmaxf(bflo(F0.x), sv.x);
    op[HW]             = fmaxf(bfhi(F0.x), sv.y);
    op[2 * (size_t)HW] = fmaxf(bflo(F0.y), sv.z);
    op[3 * (size_t)HW] = fmaxf(bfhi(F0.y), sv.w);
  }
}

extern "C" void kernel_launch(void* const* d_in, const int* in_sizes, int n_in,
                              void* d_out, int out_size, void* d_ws, size_t ws_size,
                              hipStream_t stream) {
  const float* x0  = (const float*)d_in[0];
  const float* x1  = (const float*)d_in[1];
  const float* tp  = (const float*)d_in[2];
  const float* w1  = (const float*)d_in[3];
  const float* b1  = (const float*)d_in[4];
  const float* g1  = (const float*)d_in[5];
  const float* be1 = (const float*)d_in[6];
  const float* w2  = (const float*)d_in[7];
  const float* b2  = (const float*)d_in[8];
  const float* g2  = (const float*)d_in[9];
  const float* be2 = (const float*)d_in[10];
  const float* w3  = (const float*)d_in[11];
  const float* b3  = (const float*)d_in[12];
  float* ws = (float*)d_ws;
  unsigned short* f0b = (unsigned short*)(ws + OFF_F0B);
  unsigned short* f1b = (unsigned short*)(ws + OFF_F1B);

  setup_kernel<<<119, 256, 0, stream>>>(w1, b1, g1, be1, w2, b2, g2, be2, w3, b3, ws);

  dim3 g1d(550, 4, 2);   // 64 px per block, n, input
  mlp_kernel<<<g1d, 256, 0, stream>>>(x0, x1, ws, f0b, f1b);

  dim3 g2d(550, 4);      // 64 px x 4 channel-quarters, n
  gather_max_kernel<<<g2d, 256, 0, stream>>>(f0b, f1b, tp, (float*)d_out);
}

// Round 7
// 129.597 us; speedup vs baseline: 1.4767x; 1.4767x over previous
//
#include <hip/hip_runtime.h>
#include <cmath>

#define HW   35200          // 200*176
#define CD   128            // C*D

typedef short bf16x8 __attribute__((ext_vector_type(8)));
typedef float f32x4  __attribute__((ext_vector_type(4)));

// ---- workspace float offsets ----
#define OFF_W1B   0         // w1b frag bf16 [3 kh][4 nt][64 lane][8 e] = 6144 bf16 = 3072 f
#define OFF_W2B   3072      // w2b frag bf16 [2 kh][2 nt][64][8]        = 2048 bf16 = 1024 f
#define OFF_TD    4096      // tD[d][o] fp32 (b1,be1,BN folded)           128 f
#define OFF_B2F   4224      // 32 f
#define OFF_W3F   4256      // 32 f
#define OFF_PE    4288      // peHW[hw][32] bf16 = 1126400 bf16 = 563200 f
#define OFF_F0B   567488    // f0b bf16 [4][32][HW][4] = 18022400 bf16 = 9011200 f
#define OFF_F1B   9578688   // f1b bf16 same size

__device__ __forceinline__ float lrelu(float v) { return v >= 0.f ? v : 0.01f * v; }
__device__ __forceinline__ unsigned short f2bf(float f) {   // RNE fp32->bf16
  unsigned u = __float_as_uint(f);
  u = (u + 0x7fffu + ((u >> 16) & 1u)) >> 16;
  return (unsigned short)u;
}
__device__ __forceinline__ float bflo(unsigned u) { return __uint_as_float(u << 16); }
__device__ __forceinline__ float bfhi(unsigned u) { return __uint_as_float(u & 0xffff0000u); }

// ---------------- setup: BN-folded bf16 weight frags, tD, PE table ----------------
__global__ void setup_kernel(const float* __restrict__ w1, const float* __restrict__ b1,
                             const float* __restrict__ g1, const float* __restrict__ be1,
                             const float* __restrict__ w2, const float* __restrict__ b2,
                             const float* __restrict__ g2, const float* __restrict__ be2,
                             const float* __restrict__ w3, const float* __restrict__ b3,
                             float* __restrict__ ws) {
  const float RS = rsqrtf(1.0f + 1e-5f);
  unsigned short* w1b = (unsigned short*)(ws + OFF_W1B);
  unsigned short* w2b = (unsigned short*)(ws + OFF_W2B);
  unsigned short* pe  = (unsigned short*)(ws + OFF_PE);
  int i = blockIdx.x * blockDim.x + threadIdx.x;
  if (i < 6144) {                  // w1b: B[k][n], k=kh*32+(l>>4)*8+e, n=nt*16+(l&15)
    int e = i & 7, l = (i >> 3) & 63, nt = (i >> 9) & 3, kh = i >> 11;
    int n = nt * 16 + (l & 15);
    int k = kh * 32 + (l >> 4) * 8 + e;
    int col = (kh < 2) ? k : (80 + (k - 64));   // PE slots s=k-64 map to w1 cols 80..111
    w1b[i] = f2bf(w1[n * 112 + col] * (g1[n] * RS));
    return;
  }
  i -= 6144;
  if (i < 2048) {                  // w2b
    int e = i & 7, l = (i >> 3) & 63, nt = (i >> 9) & 1, kh = i >> 10;
    int n = nt * 16 + (l & 15);
    int k = kh * 32 + (l >> 4) * 8 + e;
    w2b[i] = f2bf(w2[n * 64 + k] * (g2[n] * RS));
    return;
  }
  i -= 2048;
  if (i < 128) {                   // tD[d][o] = s1*(b1 + w1[64..79]·encD(d)) + be1
    int d = i >> 6, o = i & 63;
    float a = 0.f;
    for (int j = 0; j < 8; ++j) {
      float dv = expf((float)(2 * j) * (-0.5756462732485115f));
      float t  = (float)d * dv;
      a += w1[o * 112 + 64 + j] * sinf(t) + w1[o * 112 + 72 + j] * cosf(t);
    }
    ws[OFF_TD + d * 64 + o] = (g1[o] * RS) * (b1[o] + a) + be1[o];
    return;
  }
  i -= 128;
  if (i < 32) { ws[OFF_B2F + i] = b2[i] * (g2[i] * RS) + be2[i]; return; }
  i -= 32;
  if (i < 32) { ws[OFF_W3F + i] = w3[i]; return; }
  i -= 32;
  if (i < 563200) {                // peHW[hw][32]: slots 0-7 sinH,8-15 cosH,16-23 sinW,24-31 cosW
    int hw = i >> 4, j = i & 15;
    int h = hw / 176, w = hw - h * 176;
    int jj = j & 7;
    float dv = expf((float)(2 * jj) * (-0.5756462732485115f));
    if (j < 8) {
      float t = (float)h * dv;
      pe[hw * 32 + jj]      = f2bf(sinf(t));
      pe[hw * 32 + 8 + jj]  = f2bf(cosf(t));
    } else {
      float t = (float)w * dv;
      pe[hw * 32 + 16 + jj] = f2bf(sinf(t));
      pe[hw * 32 + 24 + jj] = f2bf(cosf(t));
    }
  }
}

// ---------------- pass 1: MFMA MLP; writes fXb = x*wt (bf16) ----------------
// Block: 64 px, M=128 rows (row = d*64+px), K=96 (64 x-ch + 32 PE-ch).
// LDS 24 KB: As[12 kgrp] with Hs overlaying kgrp 0-7 and lg/wts overlaying PE region.
__global__ __launch_bounds__(256, 6)
void mlp_kernel(const float* __restrict__ x0, const float* __restrict__ x1,
                const float* __restrict__ wtab,
                unsigned short* __restrict__ f0b, unsigned short* __restrict__ f1b) {
  __shared__ alignas(16) unsigned short As[12 * 128 * 8];  // 24 KB
  unsigned short* Hs = As;                     // overlays kgrp 0-7 (x region, dead after L1)
  float* lgp  = (float*)(As + 8 * 128 * 8);    // overlays PE region (dead after L1)
  float* wtsp = lgp + 128;

  const int t    = threadIdx.x;
  const int lane = t & 63;
  const int wv   = __builtin_amdgcn_readfirstlane(t >> 6);
  const int px   = lane;
  const int n    = blockIdx.y;
  const int inp  = blockIdx.z;
  const int hw0  = blockIdx.x * 64;
  const float* xn = (inp ? x1 : x0) + (size_t)n * CD * HW;
  unsigned short* dst = inp ? f1b : f0b;
  const unsigned short* w1bu = (const unsigned short*)(wtab + OFF_W1B);
  const unsigned short* w2bu = (const unsigned short*)(wtab + OFF_W2B);
  const unsigned short* peg  = (const unsigned short*)(wtab + OFF_PE);

  // ---- stage x (fp32->bf16) into As kgrp 0-7; KEEP values in registers ----
  unsigned xr[4][4];
#pragma unroll
  for (int i2 = 0; i2 < 4; ++i2) {
    const int md = wv * 4 + i2, d = md & 1, m = md >> 1;   // kgrp m, depth d
    float v[8];
#pragma unroll
    for (int e = 0; e < 8; ++e)
      v[e] = xn[(size_t)((m * 8 + e) * 2 + d) * HW + hw0 + px];
    uint4 uu;
    uu.x = (unsigned)f2bf(v[0]) | ((unsigned)f2bf(v[1]) << 16);
    uu.y = (unsigned)f2bf(v[2]) | ((unsigned)f2bf(v[3]) << 16);
    uu.z = (unsigned)f2bf(v[4]) | ((unsigned)f2bf(v[5]) << 16);
    uu.w = (unsigned)f2bf(v[6]) | ((unsigned)f2bf(v[7]) << 16);
    xr[i2][0] = uu.x; xr[i2][1] = uu.y; xr[i2][2] = uu.z; xr[i2][3] = uu.w;
    *(uint4*)&As[(unsigned)(m * 128 + d * 64 + px) * 8] = uu;
  }
  // PE channels into kgrp 8-11 (all 4 waves, both depth copies)
  {
    const uint4 v = *(const uint4*)(peg + (size_t)(hw0 + px) * 32 + wv * 8);
    *(uint4*)&As[(unsigned)((8 + wv) * 128 + px) * 8]      = v;
    *(uint4*)&As[(unsigned)((8 + wv) * 128 + 64 + px) * 8] = v;
  }
  __syncthreads();                                   // [1]

  // ---- layer 1: M=128 x K=96 x N=64; wave owns row-tiles {2wv, 2wv+1} ----
  const int rtb = wv * 2, dw = wv >> 1;
  f32x4 acc[2][4];
#pragma unroll
  for (int nt = 0; nt < 4; ++nt) {
    const float tdv = wtab[OFF_TD + dw * 64 + nt * 16 + (lane & 15)];
    acc[0][nt] = (f32x4){tdv, tdv, tdv, tdv};
    acc[1][nt] = acc[0][nt];
  }
#pragma unroll
  for (int kh = 0; kh < 3; ++kh) {
    const bf16x8 a0 = *(const bf16x8*)&As[(unsigned)((kh * 4 + (lane >> 4)) * 128 + (rtb + 0) * 16 + (lane & 15)) * 8];
    const bf16x8 a1 = *(const bf16x8*)&As[(unsigned)((kh * 4 + (lane >> 4)) * 128 + (rtb + 1) * 16 + (lane & 15)) * 8];
#pragma unroll
    for (int nt = 0; nt < 4; ++nt) {
      const bf16x8 b = *(const bf16x8*)&w1bu[(unsigned)((kh * 4 + nt) * 64 + lane) * 8];
      acc[0][nt] = __builtin_amdgcn_mfma_f32_16x16x32_bf16(a0, b, acc[0][nt], 0, 0, 0);
      acc[1][nt] = __builtin_amdgcn_mfma_f32_16x16x32_bf16(a1, b, acc[1][nt], 0, 0, 0);
    }
  }
  __syncthreads();                                   // [2] all L1 reads of As done

  // lrelu + h1 -> Hs (bf16, overlay); D layout: row=(l>>4)*4+r, col=l&15
#pragma unroll
  for (int rti = 0; rti < 2; ++rti)
#pragma unroll
    for (int nt = 0; nt < 4; ++nt)
#pragma unroll
      for (int r = 0; r < 4; ++r) {
        const int o   = nt * 16 + (lane & 15);
        const int row = (rtb + rti) * 16 + (lane >> 4) * 4 + r;
        Hs[(unsigned)((o >> 3) * 128 + row) * 8 + (o & 7)] = f2bf(lrelu(acc[rti][nt][r]));
      }
  __syncthreads();                                   // [3]

  // ---- layer 2: K=64 x N=32 ----
  f32x4 acc2[2][2];
#pragma unroll
  for (int nt = 0; nt < 2; ++nt) {
    const float bv = wtab[OFF_B2F + nt * 16 + (lane & 15)];
    acc2[0][nt] = (f32x4){bv, bv, bv, bv};
    acc2[1][nt] = acc2[0][nt];
  }
#pragma unroll
  for (int kh = 0; kh < 2; ++kh) {
    const bf16x8 a0 = *(const bf16x8*)&Hs[(unsigned)((kh * 4 + (lane >> 4)) * 128 + (rtb + 0) * 16 + (lane & 15)) * 8];
    const bf16x8 a1 = *(const bf16x8*)&Hs[(unsigned)((kh * 4 + (lane >> 4)) * 128 + (rtb + 1) * 16 + (lane & 15)) * 8];
#pragma unroll
    for (int nt = 0; nt < 2; ++nt) {
      const bf16x8 b = *(const bf16x8*)&w2bu[(unsigned)((kh * 2 + nt) * 64 + lane) * 8];
      acc2[0][nt] = __builtin_amdgcn_mfma_f32_16x16x32_bf16(a0, b, acc2[0][nt], 0, 0, 0);
      acc2[1][nt] = __builtin_amdgcn_mfma_f32_16x16x32_bf16(a1, b, acc2[1][nt], 0, 0, 0);
    }
  }

  // ---- layer 3 + logit reduce (b3 cancels in 2-way softmax) ----
  const float w3a = wtab[OFF_W3F + (lane & 15)];
  const float w3b = wtab[OFF_W3F + 16 + (lane & 15)];
#pragma unroll
  for (int rti = 0; rti < 2; ++rti)
#pragma unroll
    for (int r = 0; r < 4; ++r) {
      float p = w3a * lrelu(acc2[rti][0][r]) + w3b * lrelu(acc2[rti][1][r]);
      p += __shfl_xor(p, 1);
      p += __shfl_xor(p, 2);
      p += __shfl_xor(p, 4);
      p += __shfl_xor(p, 8);
      if ((lane & 15) == 0) lgp[(rtb + rti) * 16 + (lane >> 4) * 4 + r] = p;
    }
  __syncthreads();                                   // [4]

  // ---- softmax over 2 depths ----
  if (t < 128) {
    const int pp = t & 63, dd = t >> 6;
    const float lm = lgp[dd * 64 + pp], lo = lgp[(1 - dd) * 64 + pp];
    wtsp[dd * 64 + pp] = 1.f / (1.f + expf(lo - lm));
  }
  __syncthreads();                                   // [5]

  // ---- store fXb = x*wt from REGISTERS, bf16 packed [n][k][hw][4] ----
  const float w0 = wtsp[px], w1v = wtsp[64 + px];
#pragma unroll
  for (int i2 = 0; i2 < 8; ++i2) {
    const int k = wv * 8 + i2;   // planes 4k..4k+3 = (c=2k,d0),(2k,d1),(2k+1,d0),(2k+1,d1)
    const unsigned ua = xr[2 * (i2 >> 2) + 0][i2 & 3];
    const unsigned ub = xr[2 * (i2 >> 2) + 1][i2 & 3];
    const unsigned short v0 = f2bf(bflo(ua) * w0);
    const unsigned short v1 = f2bf(bflo(ub) * w1v);
    const unsigned short v2 = f2bf(bfhi(ua) * w0);
    const unsigned short v3 = f2bf(bfhi(ub) * w1v);
    uint2 pk;
    pk.x = (unsigned)v0 | ((unsigned)v1 << 16);
    pk.y = (unsigned)v2 | ((unsigned)v3 << 16);
    *(uint2*)&dst[(((size_t)n * 32 + k) * HW + hw0 + px) * 4] = pk;
  }
}

// ---------------- pass 2: pure memory — out = max(f0, bilinear(rot(f1))) ----------------
__global__ __launch_bounds__(256)
void gather_max_kernel(const unsigned short* __restrict__ f0b,
                       const unsigned short* __restrict__ f1b,
                       const float* __restrict__ tp,
                       float* __restrict__ out) {
  // bijective XCD swizzle over 550 tiles (q=68, r=6)
  const int orig = blockIdx.x;
  const int xcd = orig & 7, idx = orig >> 3;
  const int tile = (xcd < 6 ? xcd * 69 : 6 * 69 + (xcd - 6) * 68) + idx;

  const int tix = threadIdx.x;
  const int px  = tix & 63;
  const int q   = tix >> 6;
  const int n   = blockIdx.y;
  const int hw  = tile * 64 + px;
  const int h   = hw / 176;
  const int w   = hw - h * 176;

  const float thp = tp[n * 2 + 0], thc = tp[n * 2 + 1];
  const float gx = 0.2f + 0.4f * (float)w;
  const float gy = -39.8f + 0.4f * (float)h;
  const float c1 = cosf(thc),  s1v = sinf(thc);
  const float p1x = gx * c1 - gy * s1v;
  const float p1y = gx * s1v + gy * c1;
  const float c2 = cosf(-thp), s2v = sinf(-thp);
  const float p2x = p1x * c2 - p1y * s2v;
  const float p2y = p1x * s2v + p1y * c2;
  const float xi = p2x / 0.05f / 8.f;
  const float yi = (p2y - (-40.f)) / 0.05f / 8.f;

  const float xf = floorf(xi), yf = floorf(yi);
  const int x0i = (int)xf, y0i = (int)yf;
  const int x0c = min(max(x0i,     0), 175);
  const int x1c = min(max(x0i + 1, 0), 175);
  const int y0c = min(max(y0i,     0), 199);
  const int y1c = min(max(y0i + 1, 0), 199);
  const float x0f = (float)x0c, x1f = (float)x1c;
  const float y0f = (float)y0c, y1f = (float)y1c;
  const float wa = (x1f - xi) * (y1f - yi);
  const float wb = (x1f - xi) * (yi - y0f);
  const float wc = (xi - x0f) * (y1f - yi);
  const float wd = (xi - x0f) * (yi - y0f);
  const int ta = y0c * 176 + x0c, tb = y1c * 176 + x0c;
  const int tc = y0c * 176 + x1c, td = y1c * 176 + x1c;

#pragma unroll
  for (int i = 0; i < 8; ++i) {
    const int k = q * 8 + i;
    const int cd0 = k * 4;
    const unsigned short* fp1 = f1b + ((size_t)n * 32 + k) * HW * 4;
    const uint2 Ia = *(const uint2*)(fp1 + (size_t)ta * 4);
    const uint2 Ib = *(const uint2*)(fp1 + (size_t)tb * 4);
    const uint2 Ic = *(const uint2*)(fp1 + (size_t)tc * 4);
    const uint2 Id = *(const uint2*)(fp1 + (size_t)td * 4);
    float4 sv;
    sv.x = bflo(Ia.x) * wa + bflo(Ib.x) * wb + bflo(Ic.x) * wc + bflo(Id.x) * wd;
    sv.y = bfhi(Ia.x) * wa + bfhi(Ib.x) * wb + bfhi(Ic.x) * wc + bfhi(Id.x) * wd;
    sv.z = bflo(Ia.y) * wa + bflo(Ib.y) * wb + bflo(Ic.y) * wc + bflo(Id.y) * wd;
    sv.w = bfhi(Ia.y) * wa + bfhi(Ib.y) * wb + bfhi(Ic.y) * wc + bfhi(Id.y) * wd;

    const uint2 F0 = *(const uint2*)(f0b + (((size_t)n * 32 + k) * HW + hw) * 4);

    float* op = out + ((size_t)n * CD + cd0) * HW + hw;
    op[0]              = fmaxf(bflo(F0.x), sv.x);
    op[HW]             = fmaxf(bfhi(F0.x), sv.y);
    op[2 * (size_t)HW] = fmaxf(bflo(F0.y), sv.z);
    op[3 * (size_t)HW] = fmaxf(bfhi(F0.y), sv.w);
  }
}

extern "C" void kernel_launch(void* const* d_in, const int* in_sizes, int n_in,
                              void* d_out, int out_size, void* d_ws, size_t ws_size,
                              hipStream_t stream) {
  const float* x0  = (const float*)d_in[0];
  const float* x1  = (const float*)d_in[1];
  const float* tp  = (const float*)d_in[2];
  const float* w1  = (const float*)d_in[3];
  const float* b1  = (const float*)d_in[4];
  const float* g1  = (const float*)d_in[5];
  const float* be1 = (const float*)d_in[6];
  const float* w2  = (const float*)d_in[7];
  const float* b2  = (const float*)d_in[8];
  const float* g2  = (const float*)d_in[9];
  const float* be2 = (const float*)d_in[10];
  const float* w3  = (const float*)d_in[11];
  const float* b3  = (const float*)d_in[12];
  float* ws = (float*)d_ws;
  unsigned short* f0b = (unsigned short*)(ws + OFF_F0B);
  unsigned short* f1b = (unsigned short*)(ws + OFF_F1B);

  setup_kernel<<<2233, 256, 0, stream>>>(w1, b1, g1, be1, w2, b2, g2, be2, w3, b3, ws);

  dim3 g1d(550, 4, 2);   // 64 px per block, n, input
  mlp_kernel<<<g1d, 256, 0, stream>>>(x0, x1, ws, f0b, f1b);

  dim3 g2d(550, 4);      // 64 px x 4 channel-quarters, n
  gather_max_kernel<<<g2d, 256, 0, stream>>>(f0b, f1b, tp, (float*)d_out);
}

// Round 8
// 93.663 us; speedup vs baseline: 2.0432x; 1.3836x over previous
//
#include <hip/hip_runtime.h>
#include <cmath>

#define HW   35200          // 200*176
#define CD   128            // C*D

typedef short bf16x8 __attribute__((ext_vector_type(8)));
typedef float f32x4  __attribute__((ext_vector_type(4)));

// ---- workspace float offsets ----
#define OFF_W1B   0         // w1b frag bf16 [3 kh][4 nt][64 lane][8 e] = 6144 bf16 = 3072 f
#define OFF_W2B   3072      // w2b frag bf16 [2 kh][2 nt][64][8]        = 2048 bf16 = 1024 f
#define OFF_TD    4096      // tD[d][o] fp32 (b1,be1,BN folded)           128 f
#define OFF_B2F   4224      // 32 f
#define OFF_W3F   4256      // 32 f
#define OFF_PE    4288      // peHW[hw][32] bf16 = 1126400 bf16 = 563200 f
#define OFF_F0B   567488    // f0b bf16 [4][32][HW][4] = 18022400 bf16 = 9011200 f
#define OFF_F1B   9578688   // f1b bf16 same size

__device__ __forceinline__ float lrelu(float v) { return v >= 0.f ? v : 0.01f * v; }
__device__ __forceinline__ unsigned short f2bf(float f) {   // RNE fp32->bf16
  unsigned u = __float_as_uint(f);
  u = (u + 0x7fffu + ((u >> 16) & 1u)) >> 16;
  return (unsigned short)u;
}
__device__ __forceinline__ float bflo(unsigned u) { return __uint_as_float(u << 16); }
__device__ __forceinline__ float bfhi(unsigned u) { return __uint_as_float(u & 0xffff0000u); }

// ---------------- setup: BN-folded bf16 weight frags, tD, PE table ----------------
__global__ void setup_kernel(const float* __restrict__ w1, const float* __restrict__ b1,
                             const float* __restrict__ g1, const float* __restrict__ be1,
                             const float* __restrict__ w2, const float* __restrict__ b2,
                             const float* __restrict__ g2, const float* __restrict__ be2,
                             const float* __restrict__ w3, const float* __restrict__ b3,
                             float* __restrict__ ws) {
  const float RS = rsqrtf(1.0f + 1e-5f);
  unsigned short* w1b = (unsigned short*)(ws + OFF_W1B);
  unsigned short* w2b = (unsigned short*)(ws + OFF_W2B);
  unsigned short* pe  = (unsigned short*)(ws + OFF_PE);
  int i = blockIdx.x * blockDim.x + threadIdx.x;
  if (i < 6144) {                  // w1b: B[k][n], k=kh*32+(l>>4)*8+e, n=nt*16+(l&15)
    int e = i & 7, l = (i >> 3) & 63, nt = (i >> 9) & 3, kh = i >> 11;
    int n = nt * 16 + (l & 15);
    int k = kh * 32 + (l >> 4) * 8 + e;
    int col = (kh < 2) ? k : (80 + (k - 64));   // PE slots s=k-64 map to w1 cols 80..111
    w1b[i] = f2bf(w1[n * 112 + col] * (g1[n] * RS));
    return;
  }
  i -= 6144;
  if (i < 2048) {                  // w2b
    int e = i & 7, l = (i >> 3) & 63, nt = (i >> 9) & 1, kh = i >> 10;
    int n = nt * 16 + (l & 15);
    int k = kh * 32 + (l >> 4) * 8 + e;
    w2b[i] = f2bf(w2[n * 64 + k] * (g2[n] * RS));
    return;
  }
  i -= 2048;
  if (i < 128) {                   // tD[d][o] = s1*(b1 + w1[64..79]·encD(d)) + be1
    int d = i >> 6, o = i & 63;
    float a = 0.f;
    for (int j = 0; j < 8; ++j) {
      float dv = expf((float)(2 * j) * (-0.5756462732485115f));
      float t  = (float)d * dv;
      a += w1[o * 112 + 64 + j] * sinf(t) + w1[o * 112 + 72 + j] * cosf(t);
    }
    ws[OFF_TD + d * 64 + o] = (g1[o] * RS) * (b1[o] + a) + be1[o];
    return;
  }
  i -= 128;
  if (i < 32) { ws[OFF_B2F + i] = b2[i] * (g2[i] * RS) + be2[i]; return; }
  i -= 32;
  if (i < 32) { ws[OFF_W3F + i] = w3[i]; return; }
  i -= 32;
  if (i < 563200) {                // peHW[hw][32]: slots 0-7 sinH,8-15 cosH,16-23 sinW,24-31 cosW
    int hw = i >> 4, j = i & 15;
    int h = hw / 176, w = hw - h * 176;
    int jj = j & 7;
    float dv = expf((float)(2 * jj) * (-0.5756462732485115f));
    if (j < 8) {
      float t = (float)h * dv;
      pe[hw * 32 + jj]      = f2bf(sinf(t));
      pe[hw * 32 + 8 + jj]  = f2bf(cosf(t));
    } else {
      float t = (float)w * dv;
      pe[hw * 32 + 16 + jj] = f2bf(sinf(t));
      pe[hw * 32 + 24 + jj] = f2bf(cosf(t));
    }
  }
}

// ---------------- pass 1: MFMA MLP; writes fXb = x*wt (bf16) ----------------
// Block: 64 px, M=128 rows (row = d*64+px), K=96 (64 x-ch + 32 PE-ch).
// LDS 24 KB: As[12 kgrp] with Hs overlaying kgrp 0-7 and lg/wts overlaying PE region.
// launch_bounds(256,4): VGPR budget 128 — xr[4][4] must stay in registers (40-reg clamp
// at (256,6) spilled 143 MB of scratch, R7 post-mortem).
__global__ __launch_bounds__(256, 4)
void mlp_kernel(const float* __restrict__ x0, const float* __restrict__ x1,
                const float* __restrict__ wtab,
                unsigned short* __restrict__ f0b, unsigned short* __restrict__ f1b) {
  __shared__ alignas(16) unsigned short As[12 * 128 * 8];  // 24 KB
  unsigned short* Hs = As;                     // overlays kgrp 0-7 (x region, dead after L1)
  float* lgp  = (float*)(As + 8 * 128 * 8);    // overlays PE region (dead after L1)
  float* wtsp = lgp + 128;

  const int t    = threadIdx.x;
  const int lane = t & 63;
  const int wv   = __builtin_amdgcn_readfirstlane(t >> 6);
  const int px   = lane;
  const int n    = blockIdx.y;
  const int inp  = blockIdx.z;
  const int hw0  = blockIdx.x * 64;
  const float* xn = (inp ? x1 : x0) + (size_t)n * CD * HW;
  unsigned short* dst = inp ? f1b : f0b;
  const unsigned short* w1bu = (const unsigned short*)(wtab + OFF_W1B);
  const unsigned short* w2bu = (const unsigned short*)(wtab + OFF_W2B);
  const unsigned short* peg  = (const unsigned short*)(wtab + OFF_PE);

  // ---- stage x (fp32->bf16) into As kgrp 0-7; KEEP values in registers ----
  unsigned xr[4][4];
#pragma unroll
  for (int i2 = 0; i2 < 4; ++i2) {
    const int md = wv * 4 + i2, d = md & 1, m = md >> 1;   // kgrp m, depth d
    float v[8];
#pragma unroll
    for (int e = 0; e < 8; ++e)
      v[e] = xn[(size_t)((m * 8 + e) * 2 + d) * HW + hw0 + px];
    uint4 uu;
    uu.x = (unsigned)f2bf(v[0]) | ((unsigned)f2bf(v[1]) << 16);
    uu.y = (unsigned)f2bf(v[2]) | ((unsigned)f2bf(v[3]) << 16);
    uu.z = (unsigned)f2bf(v[4]) | ((unsigned)f2bf(v[5]) << 16);
    uu.w = (unsigned)f2bf(v[6]) | ((unsigned)f2bf(v[7]) << 16);
    xr[i2][0] = uu.x; xr[i2][1] = uu.y; xr[i2][2] = uu.z; xr[i2][3] = uu.w;
    *(uint4*)&As[(unsigned)(m * 128 + d * 64 + px) * 8] = uu;
  }
  // PE channels into kgrp 8-11 (all 4 waves, both depth copies)
  {
    const uint4 v = *(const uint4*)(peg + (size_t)(hw0 + px) * 32 + wv * 8);
    *(uint4*)&As[(unsigned)((8 + wv) * 128 + px) * 8]      = v;
    *(uint4*)&As[(unsigned)((8 + wv) * 128 + 64 + px) * 8] = v;
  }
  __syncthreads();                                   // [1]

  // ---- layer 1: M=128 x K=96 x N=64; wave owns row-tiles {2wv, 2wv+1} ----
  const int rtb = wv * 2, dw = wv >> 1;
  f32x4 acc[2][4];
#pragma unroll
  for (int nt = 0; nt < 4; ++nt) {
    const float tdv = wtab[OFF_TD + dw * 64 + nt * 16 + (lane & 15)];
    acc[0][nt] = (f32x4){tdv, tdv, tdv, tdv};
    acc[1][nt] = acc[0][nt];
  }
#pragma unroll
  for (int kh = 0; kh < 3; ++kh) {
    const bf16x8 a0 = *(const bf16x8*)&As[(unsigned)((kh * 4 + (lane >> 4)) * 128 + (rtb + 0) * 16 + (lane & 15)) * 8];
    const bf16x8 a1 = *(const bf16x8*)&As[(unsigned)((kh * 4 + (lane >> 4)) * 128 + (rtb + 1) * 16 + (lane & 15)) * 8];
#pragma unroll
    for (int nt = 0; nt < 4; ++nt) {
      const bf16x8 b = *(const bf16x8*)&w1bu[(unsigned)((kh * 4 + nt) * 64 + lane) * 8];
      acc[0][nt] = __builtin_amdgcn_mfma_f32_16x16x32_bf16(a0, b, acc[0][nt], 0, 0, 0);
      acc[1][nt] = __builtin_amdgcn_mfma_f32_16x16x32_bf16(a1, b, acc[1][nt], 0, 0, 0);
    }
  }
  __syncthreads();                                   // [2] all L1 reads of As done

  // lrelu + h1 -> Hs (bf16, overlay); D layout: row=(l>>4)*4+r, col=l&15
#pragma unroll
  for (int rti = 0; rti < 2; ++rti)
#pragma unroll
    for (int nt = 0; nt < 4; ++nt)
#pragma unroll
      for (int r = 0; r < 4; ++r) {
        const int o   = nt * 16 + (lane & 15);
        const int row = (rtb + rti) * 16 + (lane >> 4) * 4 + r;
        Hs[(unsigned)((o >> 3) * 128 + row) * 8 + (o & 7)] = f2bf(lrelu(acc[rti][nt][r]));
      }
  __syncthreads();                                   // [3]

  // ---- layer 2: K=64 x N=32 ----
  f32x4 acc2[2][2];
#pragma unroll
  for (int nt = 0; nt < 2; ++nt) {
    const float bv = wtab[OFF_B2F + nt * 16 + (lane & 15)];
    acc2[0][nt] = (f32x4){bv, bv, bv, bv};
    acc2[1][nt] = acc2[0][nt];
  }
#pragma unroll
  for (int kh = 0; kh < 2; ++kh) {
    const bf16x8 a0 = *(const bf16x8*)&Hs[(unsigned)((kh * 4 + (lane >> 4)) * 128 + (rtb + 0) * 16 + (lane & 15)) * 8];
    const bf16x8 a1 = *(const bf16x8*)&Hs[(unsigned)((kh * 4 + (lane >> 4)) * 128 + (rtb + 1) * 16 + (lane & 15)) * 8];
#pragma unroll
    for (int nt = 0; nt < 2; ++nt) {
      const bf16x8 b = *(const bf16x8*)&w2bu[(unsigned)((kh * 2 + nt) * 64 + lane) * 8];
      acc2[0][nt] = __builtin_amdgcn_mfma_f32_16x16x32_bf16(a0, b, acc2[0][nt], 0, 0, 0);
      acc2[1][nt] = __builtin_amdgcn_mfma_f32_16x16x32_bf16(a1, b, acc2[1][nt], 0, 0, 0);
    }
  }

  // ---- layer 3 + logit reduce (b3 cancels in 2-way softmax) ----
  const float w3a = wtab[OFF_W3F + (lane & 15)];
  const float w3b = wtab[OFF_W3F + 16 + (lane & 15)];
#pragma unroll
  for (int rti = 0; rti < 2; ++rti)
#pragma unroll
    for (int r = 0; r < 4; ++r) {
      float p = w3a * lrelu(acc2[rti][0][r]) + w3b * lrelu(acc2[rti][1][r]);
      p += __shfl_xor(p, 1);
      p += __shfl_xor(p, 2);
      p += __shfl_xor(p, 4);
      p += __shfl_xor(p, 8);
      if ((lane & 15) == 0) lgp[(rtb + rti) * 16 + (lane >> 4) * 4 + r] = p;
    }
  __syncthreads();                                   // [4]

  // ---- softmax over 2 depths ----
  if (t < 128) {
    const int pp = t & 63, dd = t >> 6;
    const float lm = lgp[dd * 64 + pp], lo = lgp[(1 - dd) * 64 + pp];
    wtsp[dd * 64 + pp] = 1.f / (1.f + expf(lo - lm));
  }
  __syncthreads();                                   // [5]

  // ---- store fXb = x*wt from REGISTERS, bf16 packed [n][k][hw][4] ----
  const float w0 = wtsp[px], w1v = wtsp[64 + px];
#pragma unroll
  for (int i2 = 0; i2 < 8; ++i2) {
    const int k = wv * 8 + i2;   // planes 4k..4k+3 = (c=2k,d0),(2k,d1),(2k+1,d0),(2k+1,d1)
    const unsigned ua = xr[2 * (i2 >> 2) + 0][i2 & 3];
    const unsigned ub = xr[2 * (i2 >> 2) + 1][i2 & 3];
    const unsigned short v0 = f2bf(bflo(ua) * w0);
    const unsigned short v1 = f2bf(bflo(ub) * w1v);
    const unsigned short v2 = f2bf(bfhi(ua) * w0);
    const unsigned short v3 = f2bf(bfhi(ub) * w1v);
    uint2 pk;
    pk.x = (unsigned)v0 | ((unsigned)v1 << 16);
    pk.y = (unsigned)v2 | ((unsigned)v3 << 16);
    *(uint2*)&dst[(((size_t)n * 32 + k) * HW + hw0 + px) * 4] = pk;
  }
}

// ---------------- pass 2: pure memory — out = max(f0, bilinear(rot(f1))) ----------------
__global__ __launch_bounds__(256)
void gather_max_kernel(const unsigned short* __restrict__ f0b,
                       const unsigned short* __restrict__ f1b,
                       const float* __restrict__ tp,
                       float* __restrict__ out) {
  // bijective XCD swizzle over 550 tiles (q=68, r=6)
  const int orig = blockIdx.x;
  const int xcd = orig & 7, idx = orig >> 3;
  const int tile = (xcd < 6 ? xcd * 69 : 6 * 69 + (xcd - 6) * 68) + idx;

  const int tix = threadIdx.x;
  const int px  = tix & 63;
  const int q   = tix >> 6;
  const int n   = blockIdx.y;
  const int hw  = tile * 64 + px;
  const int h   = hw / 176;
  const int w   = hw - h * 176;

  const float thp = tp[n * 2 + 0], thc = tp[n * 2 + 1];
  const float gx = 0.2f + 0.4f * (float)w;
  const float gy = -39.8f + 0.4f * (float)h;
  const float c1 = cosf(thc),  s1v = sinf(thc);
  const float p1x = gx * c1 - gy * s1v;
  const float p1y = gx * s1v + gy * c1;
  const float c2 = cosf(-thp), s2v = sinf(-thp);
  const float p2x = p1x * c2 - p1y * s2v;
  const float p2y = p1x * s2v + p1y * c2;
  const float xi = p2x / 0.05f / 8.f;
  const float yi = (p2y - (-40.f)) / 0.05f / 8.f;

  const float xf = floorf(xi), yf = floorf(yi);
  const int x0i = (int)xf, y0i = (int)yf;
  const int x0c = min(max(x0i,     0), 175);
  const int x1c = min(max(x0i + 1, 0), 175);
  const int y0c = min(max(y0i,     0), 199);
  const int y1c = min(max(y0i + 1, 0), 199);
  const float x0f = (float)x0c, x1f = (float)x1c;
  const float y0f = (float)y0c, y1f = (float)y1c;
  const float wa = (x1f - xi) * (y1f - yi);
  const float wb = (x1f - xi) * (yi - y0f);
  const float wc = (xi - x0f) * (y1f - yi);
  const float wd = (xi - x0f) * (yi - y0f);
  const int ta = y0c * 176 + x0c, tb = y1c * 176 + x0c;
  const int tc = y0c * 176 + x1c, td = y1c * 176 + x1c;

#pragma unroll
  for (int i = 0; i < 8; ++i) {
    const int k = q * 8 + i;
    const int cd0 = k * 4;
    const unsigned short* fp1 = f1b + ((size_t)n * 32 + k) * HW * 4;
    const uint2 Ia = *(const uint2*)(fp1 + (size_t)ta * 4);
    const uint2 Ib = *(const uint2*)(fp1 + (size_t)tb * 4);
    const uint2 Ic = *(const uint2*)(fp1 + (size_t)tc * 4);
    const uint2 Id = *(const uint2*)(fp1 + (size_t)td * 4);
    float4 sv;
    sv.x = bflo(Ia.x) * wa + bflo(Ib.x) * wb + bflo(Ic.x) * wc + bflo(Id.x) * wd;
    sv.y = bfhi(Ia.x) * wa + bfhi(Ib.x) * wb + bfhi(Ic.x) * wc + bfhi(Id.x) * wd;
    sv.z = bflo(Ia.y) * wa + bflo(Ib.y) * wb + bflo(Ic.y) * wc + bflo(Id.y) * wd;
    sv.w = bfhi(Ia.y) * wa + bfhi(Ib.y) * wb + bfhi(Ic.y) * wc + bfhi(Id.y) * wd;

    const uint2 F0 = *(const uint2*)(f0b + (((size_t)n * 32 + k) * HW + hw) * 4);

    float* op = out + ((size_t)n * CD + cd0) * HW + hw;
    op[0]              = fmaxf(bflo(F0.x), sv.x);
    op[HW]             = fmaxf(bfhi(F0.x), sv.y);
    op[2 * (size_t)HW] = fmaxf(bflo(F0.y), sv.z);
    op[3 * (size_t)HW] = fmaxf(bfhi(F0.y), sv.w);
  }
}

extern "C" void kernel_launch(void* const* d_in, const int* in_sizes, int n_in,
                              void* d_out, int out_size, void* d_ws, size_t ws_size,
                              hipStream_t stream) {
  const float* x0  = (const float*)d_in[0];
  const float* x1  = (const float*)d_in[1];
  const float* tp  = (const float*)d_in[2];
  const float* w1  = (const float*)d_in[3];
  const float* b1  = (const float*)d_in[4];
  const float* g1  = (const float*)d_in[5];
  const float* be1 = (const float*)d_in[6];
  const float* w2  = (const float*)d_in[7];
  const float* b2  = (const float*)d_in[8];
  const float* g2  = (const float*)d_in[9];
  const float* be2 = (const float*)d_in[10];
  const float* w3  = (const float*)d_in[11];
  const float* b3  = (const float*)d_in[12];
  float* ws = (float*)d_ws;
  unsigned short* f0b = (unsigned short*)(ws + OFF_F0B);
  unsigned short* f1b = (unsigned short*)(ws + OFF_F1B);

  setup_kernel<<<2233, 256, 0, stream>>>(w1, b1, g1, be1, w2, b2, g2, be2, w3, b3, ws);

  dim3 g1d(550, 4, 2);   // 64 px per block, n, input
  mlp_kernel<<<g1d, 256, 0, stream>>>(x0, x1, ws, f0b, f1b);

  dim3 g2d(550, 4);      // 64 px x 4 channel-quarters, n
  gather_max_kernel<<<g2d, 256, 0, stream>>>(f0b, f1b, tp, (float*)d_out);
}

// Round 9
// 93.531 us; speedup vs baseline: 2.0461x; 1.0014x over previous
//
#include <hip/hip_runtime.h>
#include <cmath>

#define HW   35200          // 200*176
#define CD   128            // C*D

typedef short bf16x8 __attribute__((ext_vector_type(8)));
typedef float f32x4  __attribute__((ext_vector_type(4)));

// ---- workspace float offsets ----
#define OFF_W1B   0         // w1b frag bf16 [3 kh][4 nt][64 lane][8 e] = 6144 bf16 = 3072 f
#define OFF_W2B   3072      // w2b frag bf16 [2 kh][2 nt][64][8]        = 2048 bf16 = 1024 f
#define OFF_TD    4096      // tD[d][o] fp32 (b1,be1,BN folded)           128 f
#define OFF_B2F   4224      // 32 f
#define OFF_W3F   4256      // 32 f
#define OFF_PE    4288      // peHW[hw][32] bf16 = 1126400 bf16 = 563200 f
#define OFF_F0B   567488    // f0b bf16 [4][32][HW][4] = 18022400 bf16 = 9011200 f
#define OFF_F1B   9578688   // f1b bf16 same size

__device__ __forceinline__ float lrelu(float v) { return v >= 0.f ? v : 0.01f * v; }
__device__ __forceinline__ unsigned short f2bf(float f) {   // RNE fp32->bf16
  unsigned u = __float_as_uint(f);
  u = (u + 0x7fffu + ((u >> 16) & 1u)) >> 16;
  return (unsigned short)u;
}
__device__ __forceinline__ float bflo(unsigned u) { return __uint_as_float(u << 16); }
__device__ __forceinline__ float bfhi(unsigned u) { return __uint_as_float(u & 0xffff0000u); }

// ---------------- setup: BN-folded bf16 weight frags, tD, PE table ----------------
__global__ void setup_kernel(const float* __restrict__ w1, const float* __restrict__ b1,
                             const float* __restrict__ g1, const float* __restrict__ be1,
                             const float* __restrict__ w2, const float* __restrict__ b2,
                             const float* __restrict__ g2, const float* __restrict__ be2,
                             const float* __restrict__ w3, const float* __restrict__ b3,
                             float* __restrict__ ws) {
  const float RS = rsqrtf(1.0f + 1e-5f);
  unsigned short* w1b = (unsigned short*)(ws + OFF_W1B);
  unsigned short* w2b = (unsigned short*)(ws + OFF_W2B);
  unsigned short* pe  = (unsigned short*)(ws + OFF_PE);
  int i = blockIdx.x * blockDim.x + threadIdx.x;
  if (i < 6144) {                  // w1b: B[k][n], k=kh*32+(l>>4)*8+e, n=nt*16+(l&15)
    int e = i & 7, l = (i >> 3) & 63, nt = (i >> 9) & 3, kh = i >> 11;
    int n = nt * 16 + (l & 15);
    int k = kh * 32 + (l >> 4) * 8 + e;
    int col = (kh < 2) ? k : (80 + (k - 64));   // PE slots s=k-64 map to w1 cols 80..111
    w1b[i] = f2bf(w1[n * 112 + col] * (g1[n] * RS));
    return;
  }
  i -= 6144;
  if (i < 2048) {                  // w2b
    int e = i & 7, l = (i >> 3) & 63, nt = (i >> 9) & 1, kh = i >> 10;
    int n = nt * 16 + (l & 15);
    int k = kh * 32 + (l >> 4) * 8 + e;
    w2b[i] = f2bf(w2[n * 64 + k] * (g2[n] * RS));
    return;
  }
  i -= 2048;
  if (i < 128) {                   // tD[d][o] = s1*(b1 + w1[64..79]·encD(d)) + be1
    int d = i >> 6, o = i & 63;
    float a = 0.f;
    for (int j = 0; j < 8; ++j) {
      float dv = expf((float)(2 * j) * (-0.5756462732485115f));
      float t  = (float)d * dv;
      a += w1[o * 112 + 64 + j] * sinf(t) + w1[o * 112 + 72 + j] * cosf(t);
    }
    ws[OFF_TD + d * 64 + o] = (g1[o] * RS) * (b1[o] + a) + be1[o];
    return;
  }
  i -= 128;
  if (i < 32) { ws[OFF_B2F + i] = b2[i] * (g2[i] * RS) + be2[i]; return; }
  i -= 32;
  if (i < 32) { ws[OFF_W3F + i] = w3[i]; return; }
  i -= 32;
  if (i < 563200) {                // peHW[hw][32]: slots 0-7 sinH,8-15 cosH,16-23 sinW,24-31 cosW
    int hw = i >> 4, j = i & 15;
    int h = hw / 176, w = hw - h * 176;
    int jj = j & 7;
    float dv = expf((float)(2 * jj) * (-0.5756462732485115f));
    if (j < 8) {
      float t = (float)h * dv;
      pe[hw * 32 + jj]      = f2bf(sinf(t));
      pe[hw * 32 + 8 + jj]  = f2bf(cosf(t));
    } else {
      float t = (float)w * dv;
      pe[hw * 32 + 16 + jj] = f2bf(sinf(t));
      pe[hw * 32 + 24 + jj] = f2bf(cosf(t));
    }
  }
}

// ---------------- pass 1: MFMA MLP; writes fXb = x*wt (bf16) ----------------
// Block: 64 px, M=128 rows (row = d*64+px), K=96 (64 x-ch + 32 PE-ch).
// LDS 24 KB: As[12 kgrp] with Hs overlaying kgrp 0-7 and lg/wts overlaying PE region.
// R9: T14 async-stage — issue ALL 32 x-loads to registers, then convert+write.
// launch_bounds(256,3): VGPR budget ~170 so the 32-load batch stays in flight
// (at (256,6) the 40-reg clamp spilled 143 MB scratch; at (256,4) compiler
// chose 52 regs and chunked the loads into 4 serialized latency round-trips).
__global__ __launch_bounds__(256, 3)
void mlp_kernel(const float* __restrict__ x0, const float* __restrict__ x1,
                const float* __restrict__ wtab,
                unsigned short* __restrict__ f0b, unsigned short* __restrict__ f1b) {
  __shared__ alignas(16) unsigned short As[12 * 128 * 8];  // 24 KB
  unsigned short* Hs = As;                     // overlays kgrp 0-7 (x region, dead after L1)
  float* lgp  = (float*)(As + 8 * 128 * 8);    // overlays PE region (dead after L1)
  float* wtsp = lgp + 128;

  const int t    = threadIdx.x;
  const int lane = t & 63;
  const int wv   = __builtin_amdgcn_readfirstlane(t >> 6);
  const int px   = lane;
  const int n    = blockIdx.y;
  const int inp  = blockIdx.z;
  const int hw0  = blockIdx.x * 64;
  const float* xn = (inp ? x1 : x0) + (size_t)n * CD * HW;
  unsigned short* dst = inp ? f1b : f0b;
  const unsigned short* w1bu = (const unsigned short*)(wtab + OFF_W1B);
  const unsigned short* w2bu = (const unsigned short*)(wtab + OFF_W2B);
  const unsigned short* peg  = (const unsigned short*)(wtab + OFF_PE);

  // ---- T14 stage: issue ALL 32 x-loads (+PE load) first, then convert+write ----
  float xv[32];
#pragma unroll
  for (int i2 = 0; i2 < 4; ++i2) {
    const int md = wv * 4 + i2, d = md & 1, m = md >> 1;   // kgrp m, depth d
#pragma unroll
    for (int e = 0; e < 8; ++e)
      xv[i2 * 8 + e] = xn[(size_t)((m * 8 + e) * 2 + d) * HW + hw0 + px];
  }
  const uint4 pev = *(const uint4*)(peg + (size_t)(hw0 + px) * 32 + wv * 8);

  // PE channels into kgrp 8-11 (independent of x loads — lands while x in flight)
  *(uint4*)&As[(unsigned)((8 + wv) * 128 + px) * 8]      = pev;
  *(uint4*)&As[(unsigned)((8 + wv) * 128 + 64 + px) * 8] = pev;

  unsigned xr[4][4];
#pragma unroll
  for (int i2 = 0; i2 < 4; ++i2) {
    const int md = wv * 4 + i2, m = md >> 1;   // kgrp m, depth d = md&1
    const int d  = md & 1;
    uint4 uu;
    uu.x = (unsigned)f2bf(xv[i2*8+0]) | ((unsigned)f2bf(xv[i2*8+1]) << 16);
    uu.y = (unsigned)f2bf(xv[i2*8+2]) | ((unsigned)f2bf(xv[i2*8+3]) << 16);
    uu.z = (unsigned)f2bf(xv[i2*8+4]) | ((unsigned)f2bf(xv[i2*8+5]) << 16);
    uu.w = (unsigned)f2bf(xv[i2*8+6]) | ((unsigned)f2bf(xv[i2*8+7]) << 16);
    xr[i2][0] = uu.x; xr[i2][1] = uu.y; xr[i2][2] = uu.z; xr[i2][3] = uu.w;
    *(uint4*)&As[(unsigned)(m * 128 + d * 64 + px) * 8] = uu;
  }
  __syncthreads();                                   // [1]

  // ---- layer 1: M=128 x K=96 x N=64; wave owns row-tiles {2wv, 2wv+1} ----
  const int rtb = wv * 2, dw = wv >> 1;
  f32x4 acc[2][4];
#pragma unroll
  for (int nt = 0; nt < 4; ++nt) {
    const float tdv = wtab[OFF_TD + dw * 64 + nt * 16 + (lane & 15)];
    acc[0][nt] = (f32x4){tdv, tdv, tdv, tdv};
    acc[1][nt] = acc[0][nt];
  }
#pragma unroll
  for (int kh = 0; kh < 3; ++kh) {
    const bf16x8 a0 = *(const bf16x8*)&As[(unsigned)((kh * 4 + (lane >> 4)) * 128 + (rtb + 0) * 16 + (lane & 15)) * 8];
    const bf16x8 a1 = *(const bf16x8*)&As[(unsigned)((kh * 4 + (lane >> 4)) * 128 + (rtb + 1) * 16 + (lane & 15)) * 8];
#pragma unroll
    for (int nt = 0; nt < 4; ++nt) {
      const bf16x8 b = *(const bf16x8*)&w1bu[(unsigned)((kh * 4 + nt) * 64 + lane) * 8];
      acc[0][nt] = __builtin_amdgcn_mfma_f32_16x16x32_bf16(a0, b, acc[0][nt], 0, 0, 0);
      acc[1][nt] = __builtin_amdgcn_mfma_f32_16x16x32_bf16(a1, b, acc[1][nt], 0, 0, 0);
    }
  }
  __syncthreads();                                   // [2] all L1 reads of As done

  // lrelu + h1 -> Hs (bf16, overlay); D layout: row=(l>>4)*4+r, col=l&15
#pragma unroll
  for (int rti = 0; rti < 2; ++rti)
#pragma unroll
    for (int nt = 0; nt < 4; ++nt)
#pragma unroll
      for (int r = 0; r < 4; ++r) {
        const int o   = nt * 16 + (lane & 15);
        const int row = (rtb + rti) * 16 + (lane >> 4) * 4 + r;
        Hs[(unsigned)((o >> 3) * 128 + row) * 8 + (o & 7)] = f2bf(lrelu(acc[rti][nt][r]));
      }
  __syncthreads();                                   // [3]

  // ---- layer 2: K=64 x N=32 ----
  f32x4 acc2[2][2];
#pragma unroll
  for (int nt = 0; nt < 2; ++nt) {
    const float bv = wtab[OFF_B2F + nt * 16 + (lane & 15)];
    acc2[0][nt] = (f32x4){bv, bv, bv, bv};
    acc2[1][nt] = acc2[0][nt];
  }
#pragma unroll
  for (int kh = 0; kh < 2; ++kh) {
    const bf16x8 a0 = *(const bf16x8*)&Hs[(unsigned)((kh * 4 + (lane >> 4)) * 128 + (rtb + 0) * 16 + (lane & 15)) * 8];
    const bf16x8 a1 = *(const bf16x8*)&Hs[(unsigned)((kh * 4 + (lane >> 4)) * 128 + (rtb + 1) * 16 + (lane & 15)) * 8];
#pragma unroll
    for (int nt = 0; nt < 2; ++nt) {
      const bf16x8 b = *(const bf16x8*)&w2bu[(unsigned)((kh * 2 + nt) * 64 + lane) * 8];
      acc2[0][nt] = __builtin_amdgcn_mfma_f32_16x16x32_bf16(a0, b, acc2[0][nt], 0, 0, 0);
      acc2[1][nt] = __builtin_amdgcn_mfma_f32_16x16x32_bf16(a1, b, acc2[1][nt], 0, 0, 0);
    }
  }

  // ---- layer 3 + logit reduce (b3 cancels in 2-way softmax) ----
  const float w3a = wtab[OFF_W3F + (lane & 15)];
  const float w3b = wtab[OFF_W3F + 16 + (lane & 15)];
#pragma unroll
  for (int rti = 0; rti < 2; ++rti)
#pragma unroll
    for (int r = 0; r < 4; ++r) {
      float p = w3a * lrelu(acc2[rti][0][r]) + w3b * lrelu(acc2[rti][1][r]);
      p += __shfl_xor(p, 1);
      p += __shfl_xor(p, 2);
      p += __shfl_xor(p, 4);
      p += __shfl_xor(p, 8);
      if ((lane & 15) == 0) lgp[(rtb + rti) * 16 + (lane >> 4) * 4 + r] = p;
    }
  __syncthreads();                                   // [4]

  // ---- softmax over 2 depths ----
  if (t < 128) {
    const int pp = t & 63, dd = t >> 6;
    const float lm = lgp[dd * 64 + pp], lo = lgp[(1 - dd) * 64 + pp];
    wtsp[dd * 64 + pp] = 1.f / (1.f + expf(lo - lm));
  }
  __syncthreads();                                   // [5]

  // ---- store fXb = x*wt from REGISTERS, bf16 packed [n][k][hw][4] ----
  const float w0 = wtsp[px], w1v = wtsp[64 + px];
#pragma unroll
  for (int i2 = 0; i2 < 8; ++i2) {
    const int k = wv * 8 + i2;   // planes 4k..4k+3 = (c=2k,d0),(2k,d1),(2k+1,d0),(2k+1,d1)
    const unsigned ua = xr[2 * (i2 >> 2) + 0][i2 & 3];
    const unsigned ub = xr[2 * (i2 >> 2) + 1][i2 & 3];
    const unsigned short v0 = f2bf(bflo(ua) * w0);
    const unsigned short v1 = f2bf(bflo(ub) * w1v);
    const unsigned short v2 = f2bf(bfhi(ua) * w0);
    const unsigned short v3 = f2bf(bfhi(ub) * w1v);
    uint2 pk;
    pk.x = (unsigned)v0 | ((unsigned)v1 << 16);
    pk.y = (unsigned)v2 | ((unsigned)v3 << 16);
    *(uint2*)&dst[(((size_t)n * 32 + k) * HW + hw0 + px) * 4] = pk;
  }
}

// ---------------- pass 2: pure memory — out = max(f0, bilinear(rot(f1))) ----------------
__global__ __launch_bounds__(256)
void gather_max_kernel(const unsigned short* __restrict__ f0b,
                       const unsigned short* __restrict__ f1b,
                       const float* __restrict__ tp,
                       float* __restrict__ out) {
  // bijective XCD swizzle over 550 tiles (q=68, r=6)
  const int orig = blockIdx.x;
  const int xcd = orig & 7, idx = orig >> 3;
  const int tile = (xcd < 6 ? xcd * 69 : 6 * 69 + (xcd - 6) * 68) + idx;

  const int tix = threadIdx.x;
  const int px  = tix & 63;
  const int q   = tix >> 6;
  const int n   = blockIdx.y;
  const int hw  = tile * 64 + px;
  const int h   = hw / 176;
  const int w   = hw - h * 176;

  const float thp = tp[n * 2 + 0], thc = tp[n * 2 + 1];
  const float gx = 0.2f + 0.4f * (float)w;
  const float gy = -39.8f + 0.4f * (float)h;
  const float c1 = cosf(thc),  s1v = sinf(thc);
  const float p1x = gx * c1 - gy * s1v;
  const float p1y = gx * s1v + gy * c1;
  const float c2 = cosf(-thp), s2v = sinf(-thp);
  const float p2x = p1x * c2 - p1y * s2v;
  const float p2y = p1x * s2v + p1y * c2;
  const float xi = p2x / 0.05f / 8.f;
  const float yi = (p2y - (-40.f)) / 0.05f / 8.f;

  const float xf = floorf(xi), yf = floorf(yi);
  const int x0i = (int)xf, y0i = (int)yf;
  const int x0c = min(max(x0i,     0), 175);
  const int x1c = min(max(x0i + 1, 0), 175);
  const int y0c = min(max(y0i,     0), 199);
  const int y1c = min(max(y0i + 1, 0), 199);
  const float x0f = (float)x0c, x1f = (float)x1c;
  const float y0f = (float)y0c, y1f = (float)y1c;
  const float wa = (x1f - xi) * (y1f - yi);
  const float wb = (x1f - xi) * (yi - y0f);
  const float wc = (xi - x0f) * (y1f - yi);
  const float wd = (xi - x0f) * (yi - y0f);
  const int ta = y0c * 176 + x0c, tb = y1c * 176 + x0c;
  const int tc = y0c * 176 + x1c, td = y1c * 176 + x1c;

#pragma unroll
  for (int i = 0; i < 8; ++i) {
    const int k = q * 8 + i;
    const int cd0 = k * 4;
    const unsigned short* fp1 = f1b + ((size_t)n * 32 + k) * HW * 4;
    const uint2 Ia = *(const uint2*)(fp1 + (size_t)ta * 4);
    const uint2 Ib = *(const uint2*)(fp1 + (size_t)tb * 4);
    const uint2 Ic = *(const uint2*)(fp1 + (size_t)tc * 4);
    const uint2 Id = *(const uint2*)(fp1 + (size_t)td * 4);
    float4 sv;
    sv.x = bflo(Ia.x) * wa + bflo(Ib.x) * wb + bflo(Ic.x) * wc + bflo(Id.x) * wd;
    sv.y = bfhi(Ia.x) * wa + bfhi(Ib.x) * wb + bfhi(Ic.x) * wc + bfhi(Id.x) * wd;
    sv.z = bflo(Ia.y) * wa + bflo(Ib.y) * wb + bflo(Ic.y) * wc + bflo(Id.y) * wd;
    sv.w = bfhi(Ia.y) * wa + bfhi(Ib.y) * wb + bfhi(Ic.y) * wc + bfhi(Id.y) * wd;

    const uint2 F0 = *(const uint2*)(f0b + (((size_t)n * 32 + k) * HW + hw) * 4);

    float* op = out + ((size_t)n * CD + cd0) * HW + hw;
    op[0]              = fmaxf(bflo(F0.x), sv.x);
    op[HW]             = fmaxf(bfhi(F0.x), sv.y);
    op[2 * (size_t)HW] = fmaxf(bflo(F0.y), sv.z);
    op[3 * (size_t)HW] = fmaxf(bfhi(F0.y), sv.w);
  }
}

extern "C" void kernel_launch(void* const* d_in, const int* in_sizes, int n_in,
                              void* d_out, int out_size, void* d_ws, size_t ws_size,
                              hipStream_t stream) {
  const float* x0  = (const float*)d_in[0];
  const float* x1  = (const float*)d_in[1];
  const float* tp  = (const float*)d_in[2];
  const float* w1  = (const float*)d_in[3];
  const float* b1  = (const float*)d_in[4];
  const float* g1  = (const float*)d_in[5];
  const float* be1 = (const float*)d_in[6];
  const float* w2  = (const float*)d_in[7];
  const float* b2  = (const float*)d_in[8];
  const float* g2  = (const float*)d_in[9];
  const float* be2 = (const float*)d_in[10];
  const float* w3  = (const float*)d_in[11];
  const float* b3  = (const float*)d_in[12];
  float* ws = (float*)d_ws;
  unsigned short* f0b = (unsigned short*)(ws + OFF_F0B);
  unsigned short* f1b = (unsigned short*)(ws + OFF_F1B);

  setup_kernel<<<2233, 256, 0, stream>>>(w1, b1, g1, be1, w2, b2, g2, be2, w3, b3, ws);

  dim3 g1d(550, 4, 2);   // 64 px per block, n, input
  mlp_kernel<<<g1d, 256, 0, stream>>>(x0, x1, ws, f0b, f1b);

  dim3 g2d(550, 4);      // 64 px x 4 channel-quarters, n
  gather_max_kernel<<<g2d, 256, 0, stream>>>(f0b, f1b, tp, (float*)d_out);
}

// Round 10
// 90.622 us; speedup vs baseline: 2.1118x; 1.0321x over previous
//
#include <hip/hip_runtime.h>
#include <cmath>

#define HW   35200          // 200*176
#define CD   128            // C*D

typedef short bf16x8 __attribute__((ext_vector_type(8)));
typedef float f32x4  __attribute__((ext_vector_type(4)));

union Frag { unsigned u[4]; bf16x8 v; };   // 4 VGPR = 8 bf16

// ---- workspace float offsets ----
#define OFF_W1B   0         // w1b frag bf16 [3 kh][4 nt][64 lane][8 e] = 6144 bf16 = 3072 f
#define OFF_W2B   3072      // w2b frag bf16 [2 kh][2 nt][64][8]        = 2048 bf16 = 1024 f
#define OFF_TD    4096      // tD[d][o] fp32 (b1,be1,BN folded)           128 f
#define OFF_B2F   4224      // 32 f
#define OFF_W3F   4256      // 32 f
#define OFF_PE    4288      // peHW[hw][32] bf16 = 1126400 bf16 = 563200 f
#define OFF_F0B   567488    // f0b bf16 [4][32][HW][4] = 18022400 bf16 = 9011200 f
#define OFF_F1B   9578688   // f1b bf16 same size

__device__ __forceinline__ float lrelu(float v) { return v >= 0.f ? v : 0.01f * v; }
__device__ __forceinline__ unsigned short f2bf(float f) {   // RNE fp32->bf16
  unsigned u = __float_as_uint(f);
  u = (u + 0x7fffu + ((u >> 16) & 1u)) >> 16;
  return (unsigned short)u;
}
__device__ __forceinline__ float bflo(unsigned u) { return __uint_as_float(u << 16); }
__device__ __forceinline__ float bfhi(unsigned u) { return __uint_as_float(u & 0xffff0000u); }

// ---------------- setup: BN-folded bf16 weight frags, tD, PE table ----------------
__global__ void setup_kernel(const float* __restrict__ w1, const float* __restrict__ b1,
                             const float* __restrict__ g1, const float* __restrict__ be1,
                             const float* __restrict__ w2, const float* __restrict__ b2,
                             const float* __restrict__ g2, const float* __restrict__ be2,
                             const float* __restrict__ w3, const float* __restrict__ b3,
                             float* __restrict__ ws) {
  const float RS = rsqrtf(1.0f + 1e-5f);
  unsigned short* w1b = (unsigned short*)(ws + OFF_W1B);
  unsigned short* w2b = (unsigned short*)(ws + OFF_W2B);
  unsigned short* pe  = (unsigned short*)(ws + OFF_PE);
  int i = blockIdx.x * blockDim.x + threadIdx.x;
  if (i < 6144) {                  // w1b: B[k][n], k=kh*32+(l>>4)*8+e, n=nt*16+(l&15)
    int e = i & 7, l = (i >> 3) & 63, nt = (i >> 9) & 3, kh = i >> 11;
    int n = nt * 16 + (l & 15);
    int k = kh * 32 + (l >> 4) * 8 + e;
    int col = (kh < 2) ? k : (80 + (k - 64));   // PE slots s=k-64 map to w1 cols 80..111
    w1b[i] = f2bf(w1[n * 112 + col] * (g1[n] * RS));
    return;
  }
  i -= 6144;
  if (i < 2048) {                  // w2b
    int e = i & 7, l = (i >> 3) & 63, nt = (i >> 9) & 1, kh = i >> 10;
    int n = nt * 16 + (l & 15);
    int k = kh * 32 + (l >> 4) * 8 + e;
    w2b[i] = f2bf(w2[n * 64 + k] * (g2[n] * RS));
    return;
  }
  i -= 2048;
  if (i < 128) {                   // tD[d][o] = s1*(b1 + w1[64..79]·encD(d)) + be1
    int d = i >> 6, o = i & 63;
    float a = 0.f;
    for (int j = 0; j < 8; ++j) {
      float dv = expf((float)(2 * j) * (-0.5756462732485115f));
      float t  = (float)d * dv;
      a += w1[o * 112 + 64 + j] * sinf(t) + w1[o * 112 + 72 + j] * cosf(t);
    }
    ws[OFF_TD + d * 64 + o] = (g1[o] * RS) * (b1[o] + a) + be1[o];
    return;
  }
  i -= 128;
  if (i < 32) { ws[OFF_B2F + i] = b2[i] * (g2[i] * RS) + be2[i]; return; }
  i -= 32;
  if (i < 32) { ws[OFF_W3F + i] = w3[i]; return; }
  i -= 32;
  if (i < 563200) {                // peHW[hw][32]: slots 0-7 sinH,8-15 cosH,16-23 sinW,24-31 cosW
    int hw = i >> 4, j = i & 15;
    int h = hw / 176, w = hw - h * 176;
    int jj = j & 7;
    float dv = expf((float)(2 * jj) * (-0.5756462732485115f));
    if (j < 8) {
      float t = (float)h * dv;
      pe[hw * 32 + jj]      = f2bf(sinf(t));
      pe[hw * 32 + 8 + jj]  = f2bf(cosf(t));
    } else {
      float t = (float)w * dv;
      pe[hw * 32 + 16 + jj] = f2bf(sinf(t));
      pe[hw * 32 + 24 + jj] = f2bf(cosf(t));
    }
  }
}

// ---------------- pass 1: wave-local MFMA MLP; writes fXb = x*wt (bf16) ----------------
// Block: 64 px, M=128 rows (row = d*64+px), K=96 (64 x-ch + 32 PE-ch).
// Wave wv owns tiles {wv, wv+4} = BOTH depths of px [16wv,16wv+16):
//   - A-fragments loaded directly global->reg (no As LDS, no staging barrier)
//   - h1 via wave-private Hs region (no barrier needed)
//   - layer-3 logits of both depths land in-wave -> in-register softmax
//   - f-store reuses the bf16 A-fragment registers
// Exactly one __syncthreads (wts publish; conservative).
__global__ __launch_bounds__(256, 4)
void mlp_kernel(const float* __restrict__ x0, const float* __restrict__ x1,
                const float* __restrict__ wtab,
                unsigned short* __restrict__ f0b, unsigned short* __restrict__ f1b) {
  __shared__ alignas(16) unsigned short Hs[8 * 128 * 8];  // 16 KB, wave-private rows
  __shared__ float wts[2][64];

  const int t    = threadIdx.x;
  const int lane = t & 63;
  const int wv   = __builtin_amdgcn_readfirstlane(t >> 6);
  const int g    = lane >> 4;          // k-subgroup 0..3
  const int li   = lane & 15;          // row-in-tile 0..15
  const int n    = blockIdx.y;
  const int inp  = blockIdx.z;
  const int hw0  = blockIdx.x * 64;
  const int pxs  = wv * 16 + li;       // this lane's pixel (A-frag row & store px)
  const float* xn = (inp ? x1 : x0) + (size_t)n * CD * HW;
  unsigned short* dst = inp ? f1b : f0b;
  const unsigned short* w1bu = (const unsigned short*)(wtab + OFF_W1B);
  const unsigned short* w2bu = (const unsigned short*)(wtab + OFF_W2B);
  const unsigned short* peg  = (const unsigned short*)(wtab + OFF_PE);

  // ---- direct A-fragment loads: x fp32 (ti=depth, kh=0,1) + PE uint4 (kh=2) ----
  float xf[2][2][8];
#pragma unroll
  for (int ti = 0; ti < 2; ++ti)
#pragma unroll
    for (int kh = 0; kh < 2; ++kh)
#pragma unroll
      for (int e = 0; e < 8; ++e) {
        const int c = kh * 32 + g * 8 + e;
        xf[ti][kh][e] = xn[(size_t)(c * 2 + ti) * HW + hw0 + pxs];
      }
  const uint4 pev = *(const uint4*)(peg + (size_t)(hw0 + pxs) * 32 + g * 8);

  // pack to bf16 fragments (kept live through the f-store)
  Frag xb[2][2];
#pragma unroll
  for (int ti = 0; ti < 2; ++ti)
#pragma unroll
    for (int kh = 0; kh < 2; ++kh)
#pragma unroll
      for (int q = 0; q < 4; ++q)
        xb[ti][kh].u[q] = (unsigned)f2bf(xf[ti][kh][2 * q])
                        | ((unsigned)f2bf(xf[ti][kh][2 * q + 1]) << 16);
  Frag pf;
  pf.u[0] = pev.x; pf.u[1] = pev.y; pf.u[2] = pev.z; pf.u[3] = pev.w;

  // ---- layer 1: K=96, N=64; acc init = tD (PE-D + b1 + be1 folded) ----
  f32x4 acc[2][4];
#pragma unroll
  for (int ti = 0; ti < 2; ++ti)
#pragma unroll
    for (int nt = 0; nt < 4; ++nt) {
      const float tdv = wtab[OFF_TD + ti * 64 + nt * 16 + li];
      acc[ti][nt] = (f32x4){tdv, tdv, tdv, tdv};
    }
#pragma unroll
  for (int kh = 0; kh < 2; ++kh)
#pragma unroll
    for (int nt = 0; nt < 4; ++nt) {
      const bf16x8 b = *(const bf16x8*)&w1bu[(unsigned)((kh * 4 + nt) * 64 + lane) * 8];
      acc[0][nt] = __builtin_amdgcn_mfma_f32_16x16x32_bf16(xb[0][kh].v, b, acc[0][nt], 0, 0, 0);
      acc[1][nt] = __builtin_amdgcn_mfma_f32_16x16x32_bf16(xb[1][kh].v, b, acc[1][nt], 0, 0, 0);
    }
#pragma unroll
  for (int nt = 0; nt < 4; ++nt) {
    const bf16x8 b = *(const bf16x8*)&w1bu[(unsigned)((8 + nt) * 64 + lane) * 8];
    acc[0][nt] = __builtin_amdgcn_mfma_f32_16x16x32_bf16(pf.v, b, acc[0][nt], 0, 0, 0);
    acc[1][nt] = __builtin_amdgcn_mfma_f32_16x16x32_bf16(pf.v, b, acc[1][nt], 0, 0, 0);
  }

  // ---- lrelu + h1 -> Hs (wave-private rows; no barrier) ----
#pragma unroll
  for (int ti = 0; ti < 2; ++ti) {
    const int tau = wv + ti * 4;
#pragma unroll
    for (int nt = 0; nt < 4; ++nt)
#pragma unroll
      for (int r = 0; r < 4; ++r) {
        const int o   = nt * 16 + li;
        const int row = tau * 16 + g * 4 + r;
        Hs[(unsigned)((o >> 3) * 128 + row) * 8 + (o & 7)] = f2bf(lrelu(acc[ti][nt][r]));
      }
  }

  // ---- layer 2: K=64, N=32 (reads wave's own Hs rows) ----
  f32x4 acc2[2][2];
#pragma unroll
  for (int nt = 0; nt < 2; ++nt) {
    const float bv = wtab[OFF_B2F + nt * 16 + li];
    acc2[0][nt] = (f32x4){bv, bv, bv, bv};
    acc2[1][nt] = acc2[0][nt];
  }
#pragma unroll
  for (int kh = 0; kh < 2; ++kh) {
    const bf16x8 a0 = *(const bf16x8*)&Hs[(unsigned)((kh * 4 + g) * 128 + (wv + 0) * 16 + li) * 8];
    const bf16x8 a1 = *(const bf16x8*)&Hs[(unsigned)((kh * 4 + g) * 128 + (wv + 4) * 16 + li) * 8];
#pragma unroll
    for (int nt = 0; nt < 2; ++nt) {
      const bf16x8 b = *(const bf16x8*)&w2bu[(unsigned)((kh * 2 + nt) * 64 + lane) * 8];
      acc2[0][nt] = __builtin_amdgcn_mfma_f32_16x16x32_bf16(a0, b, acc2[0][nt], 0, 0, 0);
      acc2[1][nt] = __builtin_amdgcn_mfma_f32_16x16x32_bf16(a1, b, acc2[1][nt], 0, 0, 0);
    }
  }

  // ---- layer 3 + 16-lane reduce + IN-WAVE softmax (b3 cancels) ----
  const float w3a = wtab[OFF_W3F + li];
  const float w3b = wtab[OFF_W3F + 16 + li];
  float wt0[4], wt1[4];
#pragma unroll
  for (int r = 0; r < 4; ++r) {
    float p0 = w3a * lrelu(acc2[0][0][r]) + w3b * lrelu(acc2[0][1][r]);   // d0 logit
    float p1 = w3a * lrelu(acc2[1][0][r]) + w3b * lrelu(acc2[1][1][r]);   // d1 logit
    p0 += __shfl_xor(p0, 1); p0 += __shfl_xor(p0, 2);
    p0 += __shfl_xor(p0, 4); p0 += __shfl_xor(p0, 8);
    p1 += __shfl_xor(p1, 1); p1 += __shfl_xor(p1, 2);
    p1 += __shfl_xor(p1, 4); p1 += __shfl_xor(p1, 8);
    wt0[r] = 1.f / (1.f + expf(p1 - p0));    // px = 16wv + g*4 + r
    wt1[r] = 1.f / (1.f + expf(p0 - p1));
  }
  if (li == 0) {
#pragma unroll
    for (int r = 0; r < 4; ++r) {
      wts[0][wv * 16 + g * 4 + r] = wt0[r];
      wts[1][wv * 16 + g * 4 + r] = wt1[r];
    }
  }
  __syncthreads();

  // ---- f-store from the bf16 A-fragment registers ----
  const float w0  = wts[0][pxs];
  const float w1v = wts[1][pxs];
#pragma unroll
  for (int kh = 0; kh < 2; ++kh)
#pragma unroll
    for (int j = 0; j < 4; ++j) {
      const int k = kh * 16 + g * 4 + j;        // channel-pair index; c0=2k, c1=2k+1
      const unsigned ua = xb[0][kh].u[j];       // (c0,d0) lo | (c1,d0) hi
      const unsigned ub = xb[1][kh].u[j];       // (c0,d1) lo | (c1,d1) hi
      uint2 pk;
      pk.x = (unsigned)f2bf(bflo(ua) * w0) | ((unsigned)f2bf(bflo(ub) * w1v) << 16);
      pk.y = (unsigned)f2bf(bfhi(ua) * w0) | ((unsigned)f2bf(bfhi(ub) * w1v) << 16);
      *(uint2*)&dst[(((size_t)n * 32 + k) * HW + hw0 + pxs) * 4] = pk;
    }
}

// ---------------- pass 2: pure memory — out = max(f0, bilinear(rot(f1))) ----------------
__global__ __launch_bounds__(256)
void gather_max_kernel(const unsigned short* __restrict__ f0b,
                       const unsigned short* __restrict__ f1b,
                       const float* __restrict__ tp,
                       float* __restrict__ out) {
  // bijective XCD swizzle over 550 tiles (q=68, r=6)
  const int orig = blockIdx.x;
  const int xcd = orig & 7, idx = orig >> 3;
  const int tile = (xcd < 6 ? xcd * 69 : 6 * 69 + (xcd - 6) * 68) + idx;

  const int tix = threadIdx.x;
  const int px  = tix & 63;
  const int q   = tix >> 6;
  const int n   = blockIdx.y;
  const int hw  = tile * 64 + px;
  const int h   = hw / 176;
  const int w   = hw - h * 176;

  const float thp = tp[n * 2 + 0], thc = tp[n * 2 + 1];
  const float gx = 0.2f + 0.4f * (float)w;
  const float gy = -39.8f + 0.4f * (float)h;
  const float c1 = cosf(thc),  s1v = sinf(thc);
  const float p1x = gx * c1 - gy * s1v;
  const float p1y = gx * s1v + gy * c1;
  const float c2 = cosf(-thp), s2v = sinf(-thp);
  const float p2x = p1x * c2 - p1y * s2v;
  const float p2y = p1x * s2v + p1y * c2;
  const float xi = p2x / 0.05f / 8.f;
  const float yi = (p2y - (-40.f)) / 0.05f / 8.f;

  const float xf = floorf(xi), yf = floorf(yi);
  const int x0i = (int)xf, y0i = (int)yf;
  const int x0c = min(max(x0i,     0), 175);
  const int x1c = min(max(x0i + 1, 0), 175);
  const int y0c = min(max(y0i,     0), 199);
  const int y1c = min(max(y0i + 1, 0), 199);
  const float x0f = (float)x0c, x1f = (float)x1c;
  const float y0f = (float)y0c, y1f = (float)y1c;
  const float wa = (x1f - xi) * (y1f - yi);
  const float wb = (x1f - xi) * (yi - y0f);
  const float wc = (xi - x0f) * (y1f - yi);
  const float wd = (xi - x0f) * (yi - y0f);
  const int ta = y0c * 176 + x0c, tb = y1c * 176 + x0c;
  const int tc = y0c * 176 + x1c, td = y1c * 176 + x1c;

#pragma unroll
  for (int i = 0; i < 8; ++i) {
    const int k = q * 8 + i;
    const int cd0 = k * 4;
    const unsigned short* fp1 = f1b + ((size_t)n * 32 + k) * HW * 4;
    const uint2 Ia = *(const uint2*)(fp1 + (size_t)ta * 4);
    const uint2 Ib = *(const uint2*)(fp1 + (size_t)tb * 4);
    const uint2 Ic = *(const uint2*)(fp1 + (size_t)tc * 4);
    const uint2 Id = *(const uint2*)(fp1 + (size_t)td * 4);
    float4 sv;
    sv.x = bflo(Ia.x) * wa + bflo(Ib.x) * wb + bflo(Ic.x) * wc + bflo(Id.x) * wd;
    sv.y = bfhi(Ia.x) * wa + bfhi(Ib.x) * wb + bfhi(Ic.x) * wc + bfhi(Id.x) * wd;
    sv.z = bflo(Ia.y) * wa + bflo(Ib.y) * wb + bflo(Ic.y) * wc + bflo(Id.y) * wd;
    sv.w = bfhi(Ia.y) * wa + bfhi(Ib.y) * wb + bfhi(Ic.y) * wc + bfhi(Id.y) * wd;

    const uint2 F0 = *(const uint2*)(f0b + (((size_t)n * 32 + k) * HW + hw) * 4);

    float* op = out + ((size_t)n * CD + cd0) * HW + hw;
    op[0]              = fmaxf(bflo(F0.x), sv.x);
    op[HW]             = fmaxf(bfhi(F0.x), sv.y);
    op[2 * (size_t)HW] = fmaxf(bflo(F0.y), sv.z);
    op[3 * (size_t)HW] = fmaxf(bfhi(F0.y), sv.w);
  }
}

extern "C" void kernel_launch(void* const* d_in, const int* in_sizes, int n_in,
                              void* d_out, int out_size, void* d_ws, size_t ws_size,
                              hipStream_t stream) {
  const float* x0  = (const float*)d_in[0];
  const float* x1  = (const float*)d_in[1];
  const float* tp  = (const float*)d_in[2];
  const float* w1  = (const float*)d_in[3];
  const float* b1  = (const float*)d_in[4];
  const float* g1  = (const float*)d_in[5];
  const float* be1 = (const float*)d_in[6];
  const float* w2  = (const float*)d_in[7];
  const float* b2  = (const float*)d_in[8];
  const float* g2  = (const float*)d_in[9];
  const float* be2 = (const float*)d_in[10];
  const float* w3  = (const float*)d_in[11];
  const float* b3  = (const float*)d_in[12];
  float* ws = (float*)d_ws;
  unsigned short* f0b = (unsigned short*)(ws + OFF_F0B);
  unsigned short* f1b = (unsigned short*)(ws + OFF_F1B);

  setup_kernel<<<2233, 256, 0, stream>>>(w1, b1, g1, be1, w2, b2, g2, be2, w3, b3, ws);

  dim3 g1d(550, 4, 2);   // 64 px per block, n, input
  mlp_kernel<<<g1d, 256, 0, stream>>>(x0, x1, ws, f0b, f1b);

  dim3 g2d(550, 4);      // 64 px x 4 channel-quarters, n
  gather_max_kernel<<<g2d, 256, 0, stream>>>(f0b, f1b, tp, (float*)d_out);
}